// Round 9
// baseline (414.727 us; speedup 1.0000x reference)
//
#include <hip/hip_runtime.h>
#include <hip/hip_bf16.h>

#define SLEN 512
#define BATCH 256
#define NIN 300
#define KP 320
#define NG 256
#define NH 64
#define BM 128
#define BN 128
#define BK 64
#define LDP 72   // padded LDS row length (bf16) -> 144B rows, 2-way (free) b128 reads

typedef float f32x4 __attribute__((ext_vector_type(4)));
typedef short s16x8 __attribute__((ext_vector_type(8)));
typedef short s16x4 __attribute__((ext_vector_type(4)));
typedef _Float16 f16x8 __attribute__((ext_vector_type(8)));
typedef _Float16 f16x2 __attribute__((ext_vector_type(2)));

__device__ __forceinline__ short f2bf(float f) {
  union { float f; unsigned u; } v; v.f = f;
  unsigned r = v.u + 0x7fffu + ((v.u >> 16) & 1u);  // RNE
  return (short)(r >> 16);
}

// Build WcatT[n][k] (bf16, K padded to 320), bcat[n], and Wg16[col][k] = f16(W_glt[k][col]).
__global__ void prep_w(const float* __restrict__ Wpt0, const float* __restrict__ bpt0,
                       const float* __restrict__ Wpt1, const float* __restrict__ bpt1,
                       const float* __restrict__ Wglt,
                       short* __restrict__ WcatT, float* __restrict__ bcat,
                       _Float16* __restrict__ Wg16) {
  int idx = blockIdx.x * 256 + threadIdx.x;
  if (idx < NG * KP) {
    int n = idx / KP, k = idx - n * KP;
    int g = n >> 6, h = n & 63;
    float w = 0.f;
    if (k < NIN) {
      if (h < 32) w = Wpt0[k * 128 + g * 32 + h];
      else        w = 0.5f * Wpt1[(k >> 1) * 128 + g * 32 + (h - 32)];
    }
    WcatT[idx] = f2bf(w);
  }
  if (idx < NG * NH) {  // transpose W_glt (64 x 256) -> Wg16 (256 x 64), f16
    int c = idx >> 6, k = idx & 63;
    Wg16[idx] = (_Float16)Wglt[k * NG + c];
  }
  if (idx < NG) {
    int g = idx >> 6, h = idx & 63;
    bcat[idx] = (h < 32) ? bpt0[g * 32 + h] : bpt1[g * 32 + h - 32];
  }
}

// C[row][n] = bf16(x[row]) @ WcatT^T + bcat   (row-chunk local)
__global__ __launch_bounds__(256) void gemm_i2h(
    const float* __restrict__ x, const short* __restrict__ WcatT,
    const float* __restrict__ bcat, float* __restrict__ C) {
  __shared__ short As[BM][LDP];
  __shared__ short Bs[BN][LDP];
  const int tid = threadIdx.x;
  const int m0 = blockIdx.x * BM;
  const int n0 = blockIdx.y * BN;
  const int lane = tid & 63;
  const int w = tid >> 6;
  const int wr = w >> 1, wc = w & 1;

  f32x4 acc[4][4];
#pragma unroll
  for (int m = 0; m < 4; ++m)
#pragma unroll
    for (int n = 0; n < 4; ++n) acc[m][n] = (f32x4){0.f, 0.f, 0.f, 0.f};

  const int arow_l = tid >> 4;        // 0..15
  const int acol   = (tid & 15) * 4;  // 0..60
  const int brow_l = tid >> 3;        // 0..31
  const int bcol   = (tid & 7) * 8;   // 0..56

  for (int k0 = 0; k0 < KP; k0 += BK) {
#pragma unroll
    for (int p = 0; p < 8; ++p) {
      int row = p * 16 + arow_l;
      int gk = k0 + acol;
      f32x4 v = (f32x4){0.f, 0.f, 0.f, 0.f};
      if (gk + 3 < NIN)  // 300 = 4*75 so vectors never straddle the boundary
        v = *reinterpret_cast<const f32x4*>(&x[(size_t)(m0 + row) * NIN + gk]);
      s16x4 sv;
      sv[0] = f2bf(v[0]); sv[1] = f2bf(v[1]); sv[2] = f2bf(v[2]); sv[3] = f2bf(v[3]);
      *reinterpret_cast<s16x4*>(&As[row][acol]) = sv;
    }
#pragma unroll
    for (int p = 0; p < 4; ++p) {
      int n = p * 32 + brow_l;
      s16x8 v = *reinterpret_cast<const s16x8*>(&WcatT[(size_t)(n0 + n) * KP + k0 + bcol]);
      *reinterpret_cast<s16x8*>(&Bs[n][bcol]) = v;
    }
    __syncthreads();
#pragma unroll
    for (int ks = 0; ks < 2; ++ks) {
      const int kk = ks * 32 + (lane >> 4) * 8;
      s16x8 a[4], b[4];
#pragma unroll
      for (int m = 0; m < 4; ++m)
        a[m] = *reinterpret_cast<const s16x8*>(&As[wr * 64 + m * 16 + (lane & 15)][kk]);
#pragma unroll
      for (int n = 0; n < 4; ++n)
        b[n] = *reinterpret_cast<const s16x8*>(&Bs[wc * 64 + n * 16 + (lane & 15)][kk]);
#pragma unroll
      for (int m = 0; m < 4; ++m)
#pragma unroll
        for (int n = 0; n < 4; ++n)
          acc[m][n] = __builtin_amdgcn_mfma_f32_16x16x32_bf16(a[m], b[n], acc[m][n], 0, 0, 0);
    }
    __syncthreads();
  }
  const int fc = lane & 15;
  const int fr = (lane >> 4) * 4;
#pragma unroll
  for (int n = 0; n < 4; ++n) {
    int col = n0 + wc * 64 + n * 16 + fc;
    float bias = bcat[col];
#pragma unroll
    for (int m = 0; m < 4; ++m) {
#pragma unroll
      for (int r = 0; r < 4; ++r) {
        int row = m0 + wr * 64 + m * 16 + fr + r;
        C[(size_t)row * NG + col] = acc[m][n][r] + bias;
      }
    }
  }
}

// ONE WAVE per batch row (64 threads, grid = BATCH). Lane l owns hidden unit l
// and computes all 4 of its gates in-lane: no barrier, no shuffles.
// h broadcast via 8 same-address ds_read_b128 of a 128B double-buffered LDS h.
// Weights: 32 f16x8 (128 VGPRs) register-resident via the LDS-alias trick
// (stage -> read -> overwrite: remat would be a miscompile).
// i2h deep-prefetched (quad unroll, 3 quad groups in flight, round-8 scheme).
__global__ __launch_bounds__(64, 1)
void rec_seq(
    const float* __restrict__ i2h, const _Float16* __restrict__ Wg16,
    const float* __restrict__ h_in, const float* __restrict__ c_in,
    float* __restrict__ h_state, float* __restrict__ c_state,
    float* __restrict__ hs_out, float* __restrict__ hT_out, float* __restrict__ cT_out,
    int T, int is_last) {
  const int b = blockIdx.x;
  const int l = threadIdx.x;   // 0..63

  // 32 KB LDS: stage all of Wg16 (2048 f16x8 entries), then bytes [0..256)
  // are reused (ALIASED) as the double-buffered h (2 x 64 f16).
  __shared__ __align__(16) char LB[2048 * 16];
  f16x8* Wst = reinterpret_cast<f16x8*>(LB);
  _Float16* hbuf = reinterpret_cast<_Float16*>(LB);

  for (int e = l; e < 2048; e += 64)
    Wst[e] = *reinterpret_cast<const f16x8*>(Wg16 + (size_t)e * 8);
  __syncthreads();

  // lane l, gate g, chunk kk: W_glt[k][g*64+l] for k = kk*8..kk*8+7
  f16x8 w[4][8];
#pragma unroll
  for (int g2 = 0; g2 < 4; ++g2)
#pragma unroll
    for (int kk = 0; kk < 8; ++kk)
      w[g2][kk] = Wst[(g2 * 64 + l) * 8 + kk];

  float creg = c_in[b * NH + l];
  float hreg = h_in[b * NH + l];
  __syncthreads();               // weight reads complete before overwrite
  hbuf[l] = (_Float16)hreg;      // clobbers Wst[0..15] -> weights must stay in regs
  asm volatile("s_waitcnt lgkmcnt(0)" ::: "memory");

  const size_t st = (size_t)NG * BATCH;   // i2h floats per step
  const float* ip = i2h + (size_t)b * NG + l;
  float* hp = hs_out + (size_t)b * NH + l;

#define PAIR(v, j) __builtin_shufflevector(v, v, 2*(j), 2*(j)+1)
#define D2(A, W, HV, J) A = __builtin_amdgcn_fdot2(PAIR(HV,J), PAIR(W,J), A, false);
#define DOTG(A, W, HV) D2(A,W,HV,0) D2(A,W,HV,1) D2(A,W,HV,2) D2(A,W,HV,3)
#define CHUNK(KK) { f16x8 hv = hb[KK]; \
    DOTG(af, w[0][KK], hv) DOTG(ag, w[1][KK], hv) \
    DOTG(ai, w[2][KK], hv) DOTG(ao, w[3][KK], hv) }

#define STEP(CF, CG, CI, CO, PAR) { \
    const f16x8* hb = reinterpret_cast<const f16x8*>(hbuf + (PAR) * NH); \
    float af = 0.f, ag = 0.f, ai = 0.f, ao = 0.f; \
    CHUNK(0) CHUNK(1) CHUNK(2) CHUNK(3) CHUNK(4) CHUNK(5) CHUNK(6) CHUNK(7) \
    float pf = (CF) + af, pg = (CG) + ag, pi = (CI) + ai, po = (CO) + ao; \
    pf = fminf(fmaxf(pf, -30.f), 30.f); pg = fminf(fmaxf(pg, -15.f), 15.f); \
    pi = fminf(fmaxf(pi, -30.f), 30.f); po = fminf(fmaxf(po, -30.f), 30.f); \
    float sf = 1.f / (1.f + __expf(-pf)); \
    float sg = 2.f / (1.f + __expf(-2.f * pg)) - 1.f; \
    float si = 1.f / (1.f + __expf(-pi)); \
    float so = 1.f / (1.f + __expf(-po)); \
    float c1 = sf * creg + si * sg; creg = c1; \
    float ct = fminf(fmaxf(c1, -15.f), 15.f); \
    float th = 2.f / (1.f + __expf(-2.f * ct)) - 1.f; \
    float h1 = so * th; hreg = h1; \
    hbuf[(1 - (PAR)) * NH + l] = (_Float16)h1; \
    *hp = h1; hp += st >> 2;  /* fire-and-forget; stride BATCH*NH */ \
    asm volatile("s_waitcnt lgkmcnt(0)" ::: "memory"); }

#define LD4(P, SIDX) { const float* pp = ip + (size_t)(SIDX) * st; \
    P##f = pp[0]; P##g = pp[64]; P##i = pp[128]; P##o = pp[192]; }

  int s = 0;
  if (T >= 8) {
    float c0f, c0g, c0i, c0o, c1f, c1g, c1i, c1o;
    float c2f, c2g, c2i, c2o, c3f, c3g, c3i, c3o;
    float n0f, n0g, n0i, n0o, n1f, n1g, n1i, n1o;
    float n2f, n2g, n2i, n2o, n3f, n3g, n3i, n3o;
    LD4(c0, 0) LD4(c1, 1) LD4(c2, 2) LD4(c3, 3)
    LD4(n0, 4) LD4(n1, 5) LD4(n2, 6) LD4(n3, 7)
    while (s + 4 <= T) {
      float f0f = 0.f, f0g = 0.f, f0i = 0.f, f0o = 0.f;
      float f1f = 0.f, f1g = 0.f, f1i = 0.f, f1o = 0.f;
      float f2f = 0.f, f2g = 0.f, f2i = 0.f, f2o = 0.f;
      float f3f = 0.f, f3g = 0.f, f3i = 0.f, f3o = 0.f;
      if (s + 8  < T) LD4(f0, s + 8)
      if (s + 9  < T) LD4(f1, s + 9)
      if (s + 10 < T) LD4(f2, s + 10)
      if (s + 11 < T) LD4(f3, s + 11)
      STEP(c0f, c0g, c0i, c0o, 0)
      STEP(c1f, c1g, c1i, c1o, 1)
      STEP(c2f, c2g, c2i, c2o, 0)
      STEP(c3f, c3g, c3i, c3o, 1)
      c0f = n0f; c0g = n0g; c0i = n0i; c0o = n0o;
      c1f = n1f; c1g = n1g; c1i = n1i; c1o = n1o;
      c2f = n2f; c2g = n2g; c2i = n2i; c2o = n2o;
      c3f = n3f; c3g = n3g; c3i = n3i; c3o = n3o;
      n0f = f0f; n0g = f0g; n0i = f0i; n0o = f0o;
      n1f = f1f; n1g = f1g; n1i = f1i; n1o = f1o;
      n2f = f2f; n2g = f2g; n2i = f2i; n2o = f2o;
      n3f = f3f; n3g = f3g; n3i = f3i; n3o = f3o;
      s += 4;
    }
    if (s < T) { STEP(c0f, c0g, c0i, c0o, 0) s++; }
    if (s < T) { STEP(c1f, c1g, c1i, c1o, 1) s++; }
    if (s < T) { STEP(c2f, c2g, c2i, c2o, 0) s++; }
  } else {
    while (s < T) {
      float cf, cg, ci, co;
      { const float* pp = ip + (size_t)s * st;
        cf = pp[0]; cg = pp[64]; ci = pp[128]; co = pp[192]; }
      int par = s & 1;
      STEP(cf, cg, ci, co, par)
      s++;
    }
  }

  h_state[b * NH + l] = hreg;
  c_state[b * NH + l] = creg;
  if (is_last) {
    hT_out[b * NH + l] = hreg;
    cT_out[b * NH + l] = creg;
  }
}

// decoded[idx][j] = hs[idx][:] @ Wdec[:,j] + bdec[j], idx = s*BATCH+b
__global__ __launch_bounds__(256) void decode(
    const float* __restrict__ hs, const float* __restrict__ Wdec,
    const float* __restrict__ bdec, float* __restrict__ out, int n) {
  __shared__ float wl[NH * 3];
  __shared__ float bl[3];
  const int tid = threadIdx.x;
  if (tid < NH * 3) wl[tid] = Wdec[tid];
  if (tid < 3) bl[tid] = bdec[tid];
  __syncthreads();
  int idx = blockIdx.x * 256 + tid;
  if (idx >= n) return;
  const float* hp = hs + (size_t)idx * NH;
  float d0 = 0.f, d1 = 0.f, d2 = 0.f;
#pragma unroll
  for (int k = 0; k < NH; k += 4) {
    f32x4 h4 = *reinterpret_cast<const f32x4*>(&hp[k]);
#pragma unroll
    for (int j = 0; j < 4; ++j) {
      d0 += h4[j] * wl[(k + j) * 3 + 0];
      d1 += h4[j] * wl[(k + j) * 3 + 1];
      d2 += h4[j] * wl[(k + j) * 3 + 2];
    }
  }
  out[(size_t)idx * 3 + 0] = d0 + bl[0];
  out[(size_t)idx * 3 + 1] = d1 + bl[1];
  out[(size_t)idx * 3 + 2] = d2 + bl[2];
}

extern "C" void kernel_launch(void* const* d_in, const int* in_sizes, int n_in,
                              void* d_out, int out_size, void* d_ws, size_t ws_size,
                              hipStream_t stream) {
  const float* x    = (const float*)d_in[0];
  const float* h0   = (const float*)d_in[1];
  const float* c0   = (const float*)d_in[2];
  const float* Wpt0 = (const float*)d_in[3];
  const float* bpt0 = (const float*)d_in[4];
  const float* Wpt1 = (const float*)d_in[5];
  const float* bpt1 = (const float*)d_in[6];
  const float* Wglt = (const float*)d_in[7];
  const float* Wdec = (const float*)d_in[8];
  const float* bdec = (const float*)d_in[9];
  float* out = (float*)d_out;

  char* ws = (char*)d_ws;
  short*     WcatT   = (short*)(ws);              // 163840 B
  float*     bcat    = (float*)(ws + 163840);     // 1 KB
  _Float16*  Wg16    = (_Float16*)(ws + 164864);  // 32768 B (256 x 64 f16)
  float*     h_state = (float*)(ws + 197632);     // 64 KB
  float*     c_state = (float*)(ws + 263168);     // 64 KB
  const size_t base = 328704;

  // per-step chunk bytes: i2h (256*256*4) + hs (256*64*4)
  const size_t i2h_step = (size_t)BATCH * NG * 4;
  const size_t hs_step  = (size_t)BATCH * NH * 4;
  size_t avail = (ws_size > base) ? ws_size - base : 0;
  int T = (int)(avail / (i2h_step + hs_step));
  if (T > SLEN) T = SLEN;
  if (T < 1) T = 1;

  float* i2h = (float*)(ws + base);
  float* hs  = (float*)(ws + base + (size_t)T * i2h_step);

  prep_w<<<dim3((NG * KP + 255) / 256), dim3(256), 0, stream>>>(
      Wpt0, bpt0, Wpt1, bpt1, Wglt, WcatT, bcat, Wg16);

  for (int t0 = 0; t0 < SLEN; t0 += T) {
    int Tc = (SLEN - t0 < T) ? (SLEN - t0) : T;
    dim3 g(Tc * BATCH / BM, NG / BN);
    gemm_i2h<<<g, dim3(256), 0, stream>>>(
        x + (size_t)t0 * BATCH * NIN, WcatT, bcat, i2h);
    rec_seq<<<dim3(BATCH), dim3(64), 0, stream>>>(
        i2h, Wg16,
        (t0 == 0) ? h0 : h_state, (t0 == 0) ? c0 : c_state,
        h_state, c_state, hs,
        out + (size_t)SLEN * BATCH * 3,
        out + (size_t)SLEN * BATCH * 3 + BATCH * NH,
        Tc, (t0 + Tc >= SLEN) ? 1 : 0);
    decode<<<dim3((Tc * BATCH + 255) / 256), dim3(256), 0, stream>>>(
        hs, Wdec, bdec, out + (size_t)t0 * BATCH * 3, Tc * BATCH);
  }
}